// Round 1
// baseline (419.779 us; speedup 1.0000x reference)
//
#include <hip/hip_runtime.h>

#define HM_W 240
#define HM_H 128
#define NCAM 5
#define NJ   15
#define CX   80
#define CY   80
#define CZ   20
#define NBINS (CX*CY*CZ)
#define NB   8

__device__ __forceinline__ int iclamp(int x, int lo, int hi) {
    return x < lo ? lo : (x > hi ? hi : x);
}

__global__ void __launch_bounds__(256)
project_kernel(const float* __restrict__ hm,          // [B,N,J,H,W]
               const float* __restrict__ grid_center, // [B,3]
               const float* __restrict__ R,           // [B,N,3,3]
               const float* __restrict__ T,           // [B,N,3]
               const float* __restrict__ f,           // [B,N,2]
               const float* __restrict__ c,           // [B,N,2]
               const float* __restrict__ k,           // [B,N,3]
               const float* __restrict__ p,           // [B,N,2]
               const float* __restrict__ cc,          // [B,N,2]
               const float* __restrict__ sc,          // [B,N,2]
               float* __restrict__ cubes,             // [B,J,NBINS]
               float* __restrict__ grids)             // [B,NBINS,3]
{
    const int b = blockIdx.y;
    const int v = blockIdx.x * blockDim.x + threadIdx.x;
    if (v >= NBINS) return;

    // voxel coords: v = ix*(CY*CZ) + iy*CZ + iz  (meshgrid 'ij', ravel)
    const int ix = v / (CY * CZ);
    const int rem = v - ix * (CY * CZ);
    const int iy = rem / CZ;
    const int iz = rem - iy * CZ;

    const float gcx = grid_center[b * 3 + 0];
    const float gcy = grid_center[b * 3 + 1];
    const float gcz = grid_center[b * 3 + 2];

    const float gx = -4000.0f + (float)ix * (8000.0f / 79.0f) + gcx;
    const float gy = -4000.0f + (float)iy * (8000.0f / 79.0f) + gcy;
    const float gz = -1000.0f + (float)iz * (2000.0f / 19.0f) + gcz;

    // output 1: grids [B, NBINS, 3]
    {
        float* g = grids + ((size_t)b * NBINS + v) * 3;
        g[0] = gx; g[1] = gy; g[2] = gz;
    }

    float num[NJ];
    #pragma unroll
    for (int j = 0; j < NJ; ++j) num[j] = 0.0f;
    float den = 1e-6f;

    for (int n = 0; n < NCAM; ++n) {
        const int bn = b * NCAM + n;
        const float* Rn = R + (size_t)bn * 9;
        const float* Tn = T + (size_t)bn * 3;

        const float X = gx - Tn[0];
        const float Y = gy - Tn[1];
        const float Z = gz - Tn[2];

        const float xc = Rn[0] * X + Rn[1] * Y + Rn[2] * Z;
        const float yc = Rn[3] * X + Rn[4] * Y + Rn[5] * Z;
        const float zc = Rn[6] * X + Rn[7] * Y + Rn[8] * Z;

        const float inv = 1.0f / (zc + 1e-5f);
        const float yn0 = xc * inv;
        const float yn1 = yc * inv;
        const float r2 = yn0 * yn0 + yn1 * yn1;

        const float k0 = k[bn * 3 + 0], k1 = k[bn * 3 + 1], k2 = k[bn * 3 + 2];
        const float radial = 1.0f + k0 * r2 + k1 * (r2 * r2) + k2 * (r2 * r2 * r2);
        const float p0 = p[bn * 2 + 0], p1 = p[bn * 2 + 1];
        const float tan2 = 2.0f * (p0 * yn1 + p1 * yn0);
        const float yd0 = yn0 * (radial + tan2) + p1 * r2;
        const float yd1 = yn1 * (radial + tan2) + p0 * r2;

        const float fx = f[bn * 2 + 0], fy = f[bn * 2 + 1];
        const float cxx = c[bn * 2 + 0], cyy = c[bn * 2 + 1];
        float x = fx * yd0 + cxx;
        float y = fy * yd1 + cyy;

        const float ccx = cc[bn * 2 + 0], ccy = cc[bn * 2 + 1];
        const float width = 2.0f * ccx;
        const float height = 2.0f * ccy;

        const float m = (x >= 0.0f && y >= 0.0f && x < width && y < height) ? 1.0f : 0.0f;

        const float hi = fmaxf(width, height);
        x = fminf(fmaxf(x, -1.0f), hi);
        y = fminf(fmaxf(y, -1.0f), hi);

        // get_transform(rot=0): xy = xy*(res/h200) + res*(-cc/h200 + 0.5)
        const float h200 = 200.0f * sc[bn * 2 + 0];
        const float inv_h = 1.0f / h200;
        x = x * (960.0f * inv_h) + 960.0f * (-ccx * inv_h + 0.5f);
        y = y * (512.0f * inv_h) + 512.0f * (-ccy * inv_h + 0.5f);

        // to heatmap coords
        x *= (float)HM_W / 960.0f;
        y *= (float)HM_H / 512.0f;

        // normalized grid, clipped, back to pixel coords
        float gxn = x / (float)(HM_W - 1) * 2.0f - 1.0f;
        float gyn = y / (float)(HM_H - 1) * 2.0f - 1.0f;
        gxn = fminf(fmaxf(gxn, -1.1f), 1.1f);
        gyn = fminf(fmaxf(gyn, -1.1f), 1.1f);
        const float px = (gxn + 1.0f) * 0.5f * (float)(HM_W - 1);
        const float py = (gyn + 1.0f) * 0.5f * (float)(HM_H - 1);

        // bilinear taps (zero padding)
        const float x0f = floorf(px), y0f = floorf(py);
        const float dx = px - x0f, dy = py - y0f;
        const int x0 = (int)x0f, y0 = (int)y0f;
        const int x1 = x0 + 1, y1 = y0 + 1;

        float w00 = (1.0f - dx) * (1.0f - dy);
        float w10 = dx * (1.0f - dy);
        float w01 = (1.0f - dx) * dy;
        float w11 = dx * dy;

        const bool vx0 = (x0 >= 0) & (x0 < HM_W);
        const bool vx1 = (x1 >= 0) & (x1 < HM_W);
        const bool vy0 = (y0 >= 0) & (y0 < HM_H);
        const bool vy1 = (y1 >= 0) & (y1 < HM_H);

        // fold tap validity AND camera mask into weights
        w00 = (vx0 && vy0) ? w00 * m : 0.0f;
        w10 = (vx1 && vy0) ? w10 * m : 0.0f;
        w01 = (vx0 && vy1) ? w01 * m : 0.0f;
        w11 = (vx1 && vy1) ? w11 * m : 0.0f;

        const int xa = iclamp(x0, 0, HM_W - 1);
        const int xb = iclamp(x1, 0, HM_W - 1);
        const int ya = iclamp(y0, 0, HM_H - 1);
        const int yb = iclamp(y1, 0, HM_H - 1);

        const int i00 = ya * HM_W + xa;
        const int i10 = ya * HM_W + xb;
        const int i01 = yb * HM_W + xa;
        const int i11 = yb * HM_W + xb;

        const float* base = hm + (size_t)bn * NJ * (HM_H * HM_W);
        #pragma unroll
        for (int j = 0; j < NJ; ++j) {
            const float* img = base + (size_t)j * (HM_H * HM_W);
            num[j] += w00 * img[i00] + w10 * img[i10] + w01 * img[i01] + w11 * img[i11];
        }
        den += m;
    }

    const float invden = 1.0f / den;
    const size_t outbase = (size_t)b * NJ * NBINS + v;
    #pragma unroll
    for (int j = 0; j < NJ; ++j) {
        float val = num[j] * invden;
        val = fminf(fmaxf(val, 0.0f), 1.0f);   // nan_to_num irrelevant: den >= 1e-6
        cubes[outbase + (size_t)j * NBINS] = val;
    }
}

extern "C" void kernel_launch(void* const* d_in, const int* in_sizes, int n_in,
                              void* d_out, int out_size, void* d_ws, size_t ws_size,
                              hipStream_t stream) {
    const float* hm = (const float*)d_in[0];
    const float* gc = (const float*)d_in[1];
    const float* R  = (const float*)d_in[2];
    const float* T  = (const float*)d_in[3];
    const float* f  = (const float*)d_in[4];
    const float* c  = (const float*)d_in[5];
    const float* k  = (const float*)d_in[6];
    const float* p  = (const float*)d_in[7];
    const float* cc = (const float*)d_in[8];
    const float* sc = (const float*)d_in[9];

    float* out   = (float*)d_out;
    float* cubes = out;                                  // [B,J,NBINS]
    float* grids = out + (size_t)NB * NJ * NBINS;        // [B,NBINS,3]

    dim3 block(256);
    dim3 grid((NBINS + 255) / 256, NB);
    hipLaunchKernelGGL(project_kernel, grid, block, 0, stream,
                       hm, gc, R, T, f, c, k, p, cc, sc, cubes, grids);
}

// Round 2
// 93.000 us; speedup vs baseline: 4.5137x; 4.5137x over previous
//
#include <hip/hip_runtime.h>
#include <hip/hip_fp16.h>

#define HM_W 240
#define HM_H 128
#define NCAM 5
#define NJ   15
#define CX   80
#define CY   80
#define CZ   20
#define NBINS (CX*CY*CZ)
#define NB   8
#define JPAD 16
#define HWPIX (HM_H*HM_W)

struct __align__(16) H16 { __half h[16]; };

__device__ __forceinline__ int iclamp(int x, int lo, int hi) {
    return x < lo ? lo : (x > hi ? hi : x);
}

// ---- pack/transpose: [B,N,J,H,W] f32 -> [B,N,H,W,JPAD] f16 ----
__global__ void __launch_bounds__(256)
pack_kernel(const float* __restrict__ hm, __half* __restrict__ out)
{
    const int idx = blockIdx.x * blockDim.x + threadIdx.x;   // over B*N*H*W
    if (idx >= NB * NCAM * HWPIX) return;
    const int bn = idx / HWPIX;
    const int yx = idx - bn * HWPIX;
    const float* src = hm + (size_t)bn * NJ * HWPIX + yx;
    H16 t;
    #pragma unroll
    for (int j = 0; j < NJ; ++j) t.h[j] = __float2half(src[(size_t)j * HWPIX]);
    t.h[15] = __float2half(0.0f);
    *reinterpret_cast<H16*>(out + (size_t)idx * JPAD) = t;
}

// ---- projection geometry shared by both kernels ----
struct Taps {
    int i00, i10, i01, i11;
    float w00, w10, w01, w11, m;
};

__device__ __forceinline__ Taps project_taps(
    float gx, float gy, float gz, int bn,
    const float* __restrict__ R, const float* __restrict__ T,
    const float* __restrict__ f, const float* __restrict__ c,
    const float* __restrict__ k, const float* __restrict__ p,
    const float* __restrict__ cc, const float* __restrict__ sc)
{
    const float* Rn = R + (size_t)bn * 9;
    const float* Tn = T + (size_t)bn * 3;

    const float X = gx - Tn[0];
    const float Y = gy - Tn[1];
    const float Z = gz - Tn[2];

    const float xc = Rn[0] * X + Rn[1] * Y + Rn[2] * Z;
    const float yc = Rn[3] * X + Rn[4] * Y + Rn[5] * Z;
    const float zc = Rn[6] * X + Rn[7] * Y + Rn[8] * Z;

    const float inv = 1.0f / (zc + 1e-5f);
    const float yn0 = xc * inv;
    const float yn1 = yc * inv;
    const float r2 = yn0 * yn0 + yn1 * yn1;

    const float k0 = k[bn * 3 + 0], k1 = k[bn * 3 + 1], k2 = k[bn * 3 + 2];
    const float radial = 1.0f + k0 * r2 + k1 * (r2 * r2) + k2 * (r2 * r2 * r2);
    const float p0 = p[bn * 2 + 0], p1 = p[bn * 2 + 1];
    const float tan2 = 2.0f * (p0 * yn1 + p1 * yn0);
    const float yd0 = yn0 * (radial + tan2) + p1 * r2;
    const float yd1 = yn1 * (radial + tan2) + p0 * r2;

    const float fx = f[bn * 2 + 0], fy = f[bn * 2 + 1];
    const float cxx = c[bn * 2 + 0], cyy = c[bn * 2 + 1];
    float x = fx * yd0 + cxx;
    float y = fy * yd1 + cyy;

    const float ccx = cc[bn * 2 + 0], ccy = cc[bn * 2 + 1];
    const float width = 2.0f * ccx;
    const float height = 2.0f * ccy;

    const float m = (x >= 0.0f && y >= 0.0f && x < width && y < height) ? 1.0f : 0.0f;

    const float hi = fmaxf(width, height);
    x = fminf(fmaxf(x, -1.0f), hi);
    y = fminf(fmaxf(y, -1.0f), hi);

    const float h200 = 200.0f * sc[bn * 2 + 0];
    const float inv_h = 1.0f / h200;
    x = x * (960.0f * inv_h) + 960.0f * (-ccx * inv_h + 0.5f);
    y = y * (512.0f * inv_h) + 512.0f * (-ccy * inv_h + 0.5f);

    x *= (float)HM_W / 960.0f;
    y *= (float)HM_H / 512.0f;

    float gxn = x / (float)(HM_W - 1) * 2.0f - 1.0f;
    float gyn = y / (float)(HM_H - 1) * 2.0f - 1.0f;
    gxn = fminf(fmaxf(gxn, -1.1f), 1.1f);
    gyn = fminf(fmaxf(gyn, -1.1f), 1.1f);
    const float px = (gxn + 1.0f) * 0.5f * (float)(HM_W - 1);
    const float py = (gyn + 1.0f) * 0.5f * (float)(HM_H - 1);

    const float x0f = floorf(px), y0f = floorf(py);
    const float dx = px - x0f, dy = py - y0f;
    const int x0 = (int)x0f, y0 = (int)y0f;
    const int x1 = x0 + 1, y1 = y0 + 1;

    float w00 = (1.0f - dx) * (1.0f - dy);
    float w10 = dx * (1.0f - dy);
    float w01 = (1.0f - dx) * dy;
    float w11 = dx * dy;

    const bool vx0 = (x0 >= 0) & (x0 < HM_W);
    const bool vx1 = (x1 >= 0) & (x1 < HM_W);
    const bool vy0 = (y0 >= 0) & (y0 < HM_H);
    const bool vy1 = (y1 >= 0) & (y1 < HM_H);

    Taps t;
    t.w00 = (vx0 && vy0) ? w00 * m : 0.0f;
    t.w10 = (vx1 && vy0) ? w10 * m : 0.0f;
    t.w01 = (vx0 && vy1) ? w01 * m : 0.0f;
    t.w11 = (vx1 && vy1) ? w11 * m : 0.0f;
    t.m = m;

    const int xa = iclamp(x0, 0, HM_W - 1);
    const int xb = iclamp(x1, 0, HM_W - 1);
    const int ya = iclamp(y0, 0, HM_H - 1);
    const int yb = iclamp(y1, 0, HM_H - 1);

    t.i00 = ya * HM_W + xa;
    t.i10 = ya * HM_W + xb;
    t.i01 = yb * HM_W + xa;
    t.i11 = yb * HM_W + xb;
    return t;
}

__device__ __forceinline__ void grid_coords(int b, int v,
    const float* __restrict__ grid_center, float& gx, float& gy, float& gz)
{
    const int ix = v / (CY * CZ);
    const int rem = v - ix * (CY * CZ);
    const int iy = rem / CZ;
    const int iz = rem - iy * CZ;
    gx = -4000.0f + (float)ix * (8000.0f / 79.0f) + grid_center[b * 3 + 0];
    gy = -4000.0f + (float)iy * (8000.0f / 79.0f) + grid_center[b * 3 + 1];
    gz = -1000.0f + (float)iz * (2000.0f / 19.0f) + grid_center[b * 3 + 2];
}

// ---- main kernel: packed f16 gathers ----
__global__ void __launch_bounds__(256)
project_packed(const __half* __restrict__ hmp,        // [B,N,H,W,JPAD] f16
               const float* __restrict__ grid_center,
               const float* __restrict__ R, const float* __restrict__ T,
               const float* __restrict__ f, const float* __restrict__ c,
               const float* __restrict__ k, const float* __restrict__ p,
               const float* __restrict__ cc, const float* __restrict__ sc,
               float* __restrict__ cubes, float* __restrict__ grids)
{
    const int b = blockIdx.y;
    const int v = blockIdx.x * blockDim.x + threadIdx.x;
    if (v >= NBINS) return;

    float gx, gy, gz;
    grid_coords(b, v, grid_center, gx, gy, gz);
    {
        float* g = grids + ((size_t)b * NBINS + v) * 3;
        g[0] = gx; g[1] = gy; g[2] = gz;
    }

    float num[NJ];
    #pragma unroll
    for (int j = 0; j < NJ; ++j) num[j] = 0.0f;
    float den = 1e-6f;

    for (int n = 0; n < NCAM; ++n) {
        const int bn = b * NCAM + n;
        const Taps t = project_taps(gx, gy, gz, bn, R, T, f, c, k, p, cc, sc);

        const __half* base = hmp + (size_t)bn * HWPIX * JPAD;
        const H16 t00 = *reinterpret_cast<const H16*>(base + (size_t)t.i00 * JPAD);
        const H16 t10 = *reinterpret_cast<const H16*>(base + (size_t)t.i10 * JPAD);
        const H16 t01 = *reinterpret_cast<const H16*>(base + (size_t)t.i01 * JPAD);
        const H16 t11 = *reinterpret_cast<const H16*>(base + (size_t)t.i11 * JPAD);

        #pragma unroll
        for (int j = 0; j < NJ; ++j) {
            num[j] += t.w00 * __half2float(t00.h[j]) + t.w10 * __half2float(t10.h[j])
                    + t.w01 * __half2float(t01.h[j]) + t.w11 * __half2float(t11.h[j]);
        }
        den += t.m;
    }

    const float invden = 1.0f / den;
    const size_t outbase = (size_t)b * NJ * NBINS + v;
    #pragma unroll
    for (int j = 0; j < NJ; ++j) {
        float val = num[j] * invden;
        val = fminf(fmaxf(val, 0.0f), 1.0f);
        cubes[outbase + (size_t)j * NBINS] = val;
    }
}

// ---- fallback: direct f32 gathers (round-1 kernel) ----
__global__ void __launch_bounds__(256)
project_direct(const float* __restrict__ hm,
               const float* __restrict__ grid_center,
               const float* __restrict__ R, const float* __restrict__ T,
               const float* __restrict__ f, const float* __restrict__ c,
               const float* __restrict__ k, const float* __restrict__ p,
               const float* __restrict__ cc, const float* __restrict__ sc,
               float* __restrict__ cubes, float* __restrict__ grids)
{
    const int b = blockIdx.y;
    const int v = blockIdx.x * blockDim.x + threadIdx.x;
    if (v >= NBINS) return;

    float gx, gy, gz;
    grid_coords(b, v, grid_center, gx, gy, gz);
    {
        float* g = grids + ((size_t)b * NBINS + v) * 3;
        g[0] = gx; g[1] = gy; g[2] = gz;
    }

    float num[NJ];
    #pragma unroll
    for (int j = 0; j < NJ; ++j) num[j] = 0.0f;
    float den = 1e-6f;

    for (int n = 0; n < NCAM; ++n) {
        const int bn = b * NCAM + n;
        const Taps t = project_taps(gx, gy, gz, bn, R, T, f, c, k, p, cc, sc);
        const float* base = hm + (size_t)bn * NJ * HWPIX;
        #pragma unroll
        for (int j = 0; j < NJ; ++j) {
            const float* img = base + (size_t)j * HWPIX;
            num[j] += t.w00 * img[t.i00] + t.w10 * img[t.i10]
                    + t.w01 * img[t.i01] + t.w11 * img[t.i11];
        }
        den += t.m;
    }

    const float invden = 1.0f / den;
    const size_t outbase = (size_t)b * NJ * NBINS + v;
    #pragma unroll
    for (int j = 0; j < NJ; ++j) {
        float val = num[j] * invden;
        val = fminf(fmaxf(val, 0.0f), 1.0f);
        cubes[outbase + (size_t)j * NBINS] = val;
    }
}

extern "C" void kernel_launch(void* const* d_in, const int* in_sizes, int n_in,
                              void* d_out, int out_size, void* d_ws, size_t ws_size,
                              hipStream_t stream) {
    const float* hm = (const float*)d_in[0];
    const float* gc = (const float*)d_in[1];
    const float* R  = (const float*)d_in[2];
    const float* T  = (const float*)d_in[3];
    const float* f  = (const float*)d_in[4];
    const float* c  = (const float*)d_in[5];
    const float* k  = (const float*)d_in[6];
    const float* p  = (const float*)d_in[7];
    const float* cc = (const float*)d_in[8];
    const float* sc = (const float*)d_in[9];

    float* out   = (float*)d_out;
    float* cubes = out;                                  // [B,J,NBINS]
    float* grids = out + (size_t)NB * NJ * NBINS;        // [B,NBINS,3]

    dim3 block(256);
    dim3 grid((NBINS + 255) / 256, NB);

    const size_t need = (size_t)NB * NCAM * HWPIX * JPAD * sizeof(__half) + 64;
    if (ws_size >= need) {
        __half* hmp = (__half*)d_ws;
        const int npix = NB * NCAM * HWPIX;
        hipLaunchKernelGGL(pack_kernel, dim3((npix + 255) / 256), block, 0, stream,
                           hm, hmp);
        hipLaunchKernelGGL(project_packed, grid, block, 0, stream,
                           hmp, gc, R, T, f, c, k, p, cc, sc, cubes, grids);
    } else {
        hipLaunchKernelGGL(project_direct, grid, block, 0, stream,
                           hm, gc, R, T, f, c, k, p, cc, sc, cubes, grids);
    }
}

// Round 3
// 78.032 us; speedup vs baseline: 5.3796x; 1.1918x over previous
//
#include <hip/hip_runtime.h>

#define HM_W 240
#define HM_H 128
#define NCAM 5
#define NJ   15
#define CX   80
#define CY   80
#define CZ   20
#define NBINS (CX*CY*CZ)
#define NB   8
#define HWPIX (HM_H*HM_W)

__device__ __forceinline__ int iclamp(int x, int lo, int hi) {
    return x < lo ? lo : (x > hi ? hi : x);
}

// ---- pack: [B,N,J,H,W] f32 -> [B,N,H,W,16] u8 (val*255, rounded) ----
__global__ void __launch_bounds__(256)
pack_u8(const float* __restrict__ hm, uint4* __restrict__ out)
{
    const int idx = blockIdx.x * blockDim.x + threadIdx.x;   // over B*N*H*W
    if (idx >= NB * NCAM * HWPIX) return;
    const int bn = idx / HWPIX;
    const int yx = idx - bn * HWPIX;
    const float* src = hm + (size_t)bn * NJ * HWPIX + yx;
    unsigned b[16];
    #pragma unroll
    for (int j = 0; j < NJ; ++j) {
        float v = src[(size_t)j * HWPIX];
        v = fminf(fmaxf(v, 0.0f), 1.0f);
        b[j] = (unsigned)fmaf(v, 255.0f, 0.5f);
    }
    b[15] = 0u;
    uint4 q;
    q.x = b[0]  | (b[1]  << 8) | (b[2]  << 16) | (b[3]  << 24);
    q.y = b[4]  | (b[5]  << 8) | (b[6]  << 16) | (b[7]  << 24);
    q.z = b[8]  | (b[9]  << 8) | (b[10] << 16) | (b[11] << 24);
    q.w = b[12] | (b[13] << 8) | (b[14] << 16);
    out[idx] = q;
}

struct TapsU {
    int i00, i10, i01, i11;
    float w00, w10, w01, w11, m;
};

// distortion + affine-to-heatmap + bilinear tap/weight computation.
// Ax,Bx,Ay,By: fused affine from clipped pixel coords to normalized grid g.
__device__ __forceinline__ TapsU make_taps(
    float xc, float yc, float zc,
    float k0, float k1, float k2, float p0, float p1,
    float fx, float fy, float cxx, float cyy,
    float width, float height, float himax,
    float Ax, float Bx, float Ay, float By)
{
    const float inv = 1.0f / (zc + 1e-5f);
    const float yn0 = xc * inv;
    const float yn1 = yc * inv;
    const float r2 = yn0 * yn0 + yn1 * yn1;
    const float radial = 1.0f + k0 * r2 + k1 * (r2 * r2) + k2 * (r2 * r2 * r2);
    const float tan2 = 2.0f * (p0 * yn1 + p1 * yn0);
    const float yd0 = yn0 * (radial + tan2) + p1 * r2;
    const float yd1 = yn1 * (radial + tan2) + p0 * r2;

    float x = fmaf(fx, yd0, cxx);
    float y = fmaf(fy, yd1, cyy);

    const float m = (x >= 0.0f && y >= 0.0f && x < width && y < height) ? 1.0f : 0.0f;

    x = fminf(fmaxf(x, -1.0f), himax);
    y = fminf(fmaxf(y, -1.0f), himax);

    float gx = fmaf(Ax, x, Bx);
    float gy = fmaf(Ay, y, By);
    gx = fminf(fmaxf(gx, -1.1f), 1.1f);
    gy = fminf(fmaxf(gy, -1.1f), 1.1f);
    const float px = (gx + 1.0f) * (0.5f * (HM_W - 1));
    const float py = (gy + 1.0f) * (0.5f * (HM_H - 1));

    const float x0f = floorf(px), y0f = floorf(py);
    const float dx = px - x0f, dy = py - y0f;
    const int x0 = (int)x0f, y0 = (int)y0f;
    const int x1 = x0 + 1, y1 = y0 + 1;

    float w00 = (1.0f - dx) * (1.0f - dy);
    float w10 = dx * (1.0f - dy);
    float w01 = (1.0f - dx) * dy;
    float w11 = dx * dy;

    const bool vx0 = (x0 >= 0) & (x0 < HM_W);
    const bool vx1 = (x1 >= 0) & (x1 < HM_W);
    const bool vy0 = (y0 >= 0) & (y0 < HM_H);
    const bool vy1 = (y1 >= 0) & (y1 < HM_H);

    TapsU t;
    t.w00 = (vx0 && vy0) ? w00 * m : 0.0f;
    t.w10 = (vx1 && vy0) ? w10 * m : 0.0f;
    t.w01 = (vx0 && vy1) ? w01 * m : 0.0f;
    t.w11 = (vx1 && vy1) ? w11 * m : 0.0f;
    t.m = m;

    const int xa = iclamp(x0, 0, HM_W - 1);
    const int xb = iclamp(x1, 0, HM_W - 1);
    const int ya = iclamp(y0, 0, HM_H - 1);
    const int yb = iclamp(y1, 0, HM_H - 1);

    t.i00 = ya * HM_W + xa;
    t.i10 = ya * HM_W + xb;
    t.i01 = yb * HM_W + xa;
    t.i11 = yb * HM_W + xb;
    return t;
}

__device__ __forceinline__ void accum_u8(const uint4* __restrict__ base,
                                         const TapsU& t, float* __restrict__ num)
{
    const uint4 q00 = base[t.i00];
    const uint4 q10 = base[t.i10];
    const uint4 q01 = base[t.i01];
    const uint4 q11 = base[t.i11];
    const unsigned* a00 = (const unsigned*)&q00;
    const unsigned* a10 = (const unsigned*)&q10;
    const unsigned* a01 = (const unsigned*)&q01;
    const unsigned* a11 = (const unsigned*)&q11;
    #pragma unroll
    for (int j = 0; j < NJ; ++j) {
        const int d = j >> 2, sh = (j & 3) * 8;
        const float v00 = (float)((a00[d] >> sh) & 0xffu);
        const float v10 = (float)((a10[d] >> sh) & 0xffu);
        const float v01 = (float)((a01[d] >> sh) & 0xffu);
        const float v11 = (float)((a11[d] >> sh) & 0xffu);
        num[j] = fmaf(t.w00, v00, num[j]);
        num[j] = fmaf(t.w10, v10, num[j]);
        num[j] = fmaf(t.w01, v01, num[j]);
        num[j] = fmaf(t.w11, v11, num[j]);
    }
}

// ---- main kernel: 2 z-adjacent voxels per thread, u8 packed gathers ----
__global__ void __launch_bounds__(256)
project_u8(const uint4* __restrict__ hmp,             // [B,N,H,W] of 16-byte pixels
           const float* __restrict__ grid_center,
           const float* __restrict__ R, const float* __restrict__ T,
           const float* __restrict__ f, const float* __restrict__ c,
           const float* __restrict__ k, const float* __restrict__ p,
           const float* __restrict__ cc, const float* __restrict__ sc,
           float* __restrict__ cubes, float* __restrict__ grids)
{
    const int b = blockIdx.y;
    const int v2 = blockIdx.x * blockDim.x + threadIdx.x;    // voxel-pair index
    if (v2 >= NBINS / 2) return;

    const int col = v2 / (CZ / 2);         // x*CY + y
    const int tz  = v2 - col * (CZ / 2);
    const int ix = col / CY;
    const int iy = col - ix * CY;
    const int iz0 = 2 * tz;
    const int v0 = col * CZ + iz0;

    const float gcx = grid_center[b * 3 + 0];
    const float gcy = grid_center[b * 3 + 1];
    const float gcz = grid_center[b * 3 + 2];

    const float gx = -4000.0f + (float)ix * (8000.0f / 79.0f) + gcx;
    const float gy = -4000.0f + (float)iy * (8000.0f / 79.0f) + gcy;
    const float gz0 = -1000.0f + (float)iz0 * (2000.0f / 19.0f) + gcz;
    const float gz1 = gz0 + (2000.0f / 19.0f);

    {   // grids output: 6 consecutive floats
        float* g = grids + ((size_t)b * NBINS + v0) * 3;
        g[0] = gx; g[1] = gy; g[2] = gz0;
        g[3] = gx; g[4] = gy; g[5] = gz1;
    }

    float num0[NJ], num1[NJ];
    #pragma unroll
    for (int j = 0; j < NJ; ++j) { num0[j] = 0.0f; num1[j] = 0.0f; }
    float den0 = 1e-6f, den1 = 1e-6f;

    for (int n = 0; n < NCAM; ++n) {
        const int bn = b * NCAM + n;
        const float* Rn = R + (size_t)bn * 9;
        const float* Tn = T + (size_t)bn * 3;

        const float X = gx - Tn[0];
        const float Y = gy - Tn[1];
        const float Z0 = gz0 - Tn[2];
        const float Z1 = gz1 - Tn[2];

        // shared partials across the voxel pair
        const float xp = Rn[0] * X + Rn[1] * Y;
        const float yp = Rn[3] * X + Rn[4] * Y;
        const float zp = Rn[6] * X + Rn[7] * Y;

        const float k0 = k[bn * 3 + 0], k1 = k[bn * 3 + 1], k2 = k[bn * 3 + 2];
        const float p0 = p[bn * 2 + 0], p1 = p[bn * 2 + 1];
        const float fx = f[bn * 2 + 0], fy = f[bn * 2 + 1];
        const float cxx = c[bn * 2 + 0], cyy = c[bn * 2 + 1];
        const float ccx = cc[bn * 2 + 0], ccy = cc[bn * 2 + 1];
        const float width = 2.0f * ccx, height = 2.0f * ccy;
        const float himax = fmaxf(width, height);

        // fused affine: clipped-pixel -> normalized grid coord
        const float inv_h = 1.0f / (200.0f * sc[bn * 2 + 0]);
        const float Ax = (2.0f * (float)HM_W / (float)(HM_W - 1)) * inv_h;
        const float Bx = (0.5f - ccx * inv_h) * (2.0f * (float)HM_W / (float)(HM_W - 1)) - 1.0f;
        const float Ay = (2.0f * (float)HM_H / (float)(HM_H - 1)) * inv_h;
        const float By = (0.5f - ccy * inv_h) * (2.0f * (float)HM_H / (float)(HM_H - 1)) - 1.0f;

        const TapsU t0 = make_taps(fmaf(Rn[2], Z0, xp), fmaf(Rn[5], Z0, yp), fmaf(Rn[8], Z0, zp),
                                   k0, k1, k2, p0, p1, fx, fy, cxx, cyy,
                                   width, height, himax, Ax, Bx, Ay, By);
        const TapsU t1 = make_taps(fmaf(Rn[2], Z1, xp), fmaf(Rn[5], Z1, yp), fmaf(Rn[8], Z1, zp),
                                   k0, k1, k2, p0, p1, fx, fy, cxx, cyy,
                                   width, height, himax, Ax, Bx, Ay, By);

        const uint4* base = hmp + (size_t)bn * HWPIX;
        accum_u8(base, t0, num0);
        accum_u8(base, t1, num1);
        den0 += t0.m;
        den1 += t1.m;
    }

    const float s0 = (1.0f / 255.0f) / den0;
    const float s1 = (1.0f / 255.0f) / den1;
    const size_t outbase = (size_t)b * NJ * NBINS + v0;
    #pragma unroll
    for (int j = 0; j < NJ; ++j) {
        float2 o;
        o.x = fminf(fmaxf(num0[j] * s0, 0.0f), 1.0f);
        o.y = fminf(fmaxf(num1[j] * s1, 0.0f), 1.0f);
        *reinterpret_cast<float2*>(cubes + outbase + (size_t)j * NBINS) = o;
    }
}

// ---- fallback: direct f32 gathers (round-1 kernel, used only if ws too small) ----
__global__ void __launch_bounds__(256)
project_direct(const float* __restrict__ hm,
               const float* __restrict__ grid_center,
               const float* __restrict__ R, const float* __restrict__ T,
               const float* __restrict__ f, const float* __restrict__ c,
               const float* __restrict__ k, const float* __restrict__ p,
               const float* __restrict__ cc, const float* __restrict__ sc,
               float* __restrict__ cubes, float* __restrict__ grids)
{
    const int b = blockIdx.y;
    const int v = blockIdx.x * blockDim.x + threadIdx.x;
    if (v >= NBINS) return;

    const int ix = v / (CY * CZ);
    const int rem = v - ix * (CY * CZ);
    const int iy = rem / CZ;
    const int iz = rem - iy * CZ;

    const float gx = -4000.0f + (float)ix * (8000.0f / 79.0f) + grid_center[b * 3 + 0];
    const float gy = -4000.0f + (float)iy * (8000.0f / 79.0f) + grid_center[b * 3 + 1];
    const float gz = -1000.0f + (float)iz * (2000.0f / 19.0f) + grid_center[b * 3 + 2];

    {
        float* g = grids + ((size_t)b * NBINS + v) * 3;
        g[0] = gx; g[1] = gy; g[2] = gz;
    }

    float num[NJ];
    #pragma unroll
    for (int j = 0; j < NJ; ++j) num[j] = 0.0f;
    float den = 1e-6f;

    for (int n = 0; n < NCAM; ++n) {
        const int bn = b * NCAM + n;
        const float* Rn = R + (size_t)bn * 9;
        const float* Tn = T + (size_t)bn * 3;
        const float X = gx - Tn[0], Y = gy - Tn[1], Z = gz - Tn[2];

        const float ccx = cc[bn * 2 + 0], ccy = cc[bn * 2 + 1];
        const float width = 2.0f * ccx, height = 2.0f * ccy;
        const float inv_h = 1.0f / (200.0f * sc[bn * 2 + 0]);
        const float Ax = (2.0f * (float)HM_W / (float)(HM_W - 1)) * inv_h;
        const float Bx = (0.5f - ccx * inv_h) * (2.0f * (float)HM_W / (float)(HM_W - 1)) - 1.0f;
        const float Ay = (2.0f * (float)HM_H / (float)(HM_H - 1)) * inv_h;
        const float By = (0.5f - ccy * inv_h) * (2.0f * (float)HM_H / (float)(HM_H - 1)) - 1.0f;

        const TapsU t = make_taps(
            Rn[0]*X + Rn[1]*Y + Rn[2]*Z, Rn[3]*X + Rn[4]*Y + Rn[5]*Z, Rn[6]*X + Rn[7]*Y + Rn[8]*Z,
            k[bn*3+0], k[bn*3+1], k[bn*3+2], p[bn*2+0], p[bn*2+1],
            f[bn*2+0], f[bn*2+1], c[bn*2+0], c[bn*2+1],
            width, height, fmaxf(width, height), Ax, Bx, Ay, By);

        const float* base = hm + (size_t)bn * NJ * HWPIX;
        #pragma unroll
        for (int j = 0; j < NJ; ++j) {
            const float* img = base + (size_t)j * HWPIX;
            num[j] += t.w00 * img[t.i00] + t.w10 * img[t.i10]
                    + t.w01 * img[t.i01] + t.w11 * img[t.i11];
        }
        den += t.m;
    }

    const float invden = 1.0f / den;
    const size_t outbase = (size_t)b * NJ * NBINS + v;
    #pragma unroll
    for (int j = 0; j < NJ; ++j) {
        float val = num[j] * invden;
        val = fminf(fmaxf(val, 0.0f), 1.0f);
        cubes[outbase + (size_t)j * NBINS] = val;
    }
}

extern "C" void kernel_launch(void* const* d_in, const int* in_sizes, int n_in,
                              void* d_out, int out_size, void* d_ws, size_t ws_size,
                              hipStream_t stream) {
    const float* hm = (const float*)d_in[0];
    const float* gc = (const float*)d_in[1];
    const float* R  = (const float*)d_in[2];
    const float* T  = (const float*)d_in[3];
    const float* f  = (const float*)d_in[4];
    const float* c  = (const float*)d_in[5];
    const float* k  = (const float*)d_in[6];
    const float* p  = (const float*)d_in[7];
    const float* cc = (const float*)d_in[8];
    const float* sc = (const float*)d_in[9];

    float* out   = (float*)d_out;
    float* cubes = out;                                  // [B,J,NBINS]
    float* grids = out + (size_t)NB * NJ * NBINS;        // [B,NBINS,3]

    const size_t need = (size_t)NB * NCAM * HWPIX * 16 + 64;
    if (ws_size >= need) {
        uint4* hmp = (uint4*)d_ws;
        const int npix = NB * NCAM * HWPIX;
        hipLaunchKernelGGL(pack_u8, dim3((npix + 255) / 256), dim3(256), 0, stream,
                           hm, hmp);
        dim3 grid((NBINS / 2 + 255) / 256, NB);
        hipLaunchKernelGGL(project_u8, grid, dim3(256), 0, stream,
                           hmp, gc, R, T, f, c, k, p, cc, sc, cubes, grids);
    } else {
        dim3 grid((NBINS + 255) / 256, NB);
        hipLaunchKernelGGL(project_direct, grid, dim3(256), 0, stream,
                           hm, gc, R, T, f, c, k, p, cc, sc, cubes, grids);
    }
}

// Round 4
// 60.379 us; speedup vs baseline: 6.9524x; 1.2924x over previous
//
#include <hip/hip_runtime.h>

#define HM_W 240
#define HM_H 128
#define NCAM 5
#define NJ   15
#define CX   80
#define CY   80
#define CZ   20
#define NBINS (CX*CY*CZ)
#define NB   8
#define HWPIX (HM_H*HM_W)

__device__ __forceinline__ int iclamp(int x, int lo, int hi) {
    return x < lo ? lo : (x > hi ? hi : x);
}

// ---- pack: [B,N,J,H,W] f32 -> [B,N,H,W,16] u8 (val*255, rounded) ----
// 1-D grid, batch = blockIdx.x & 7 so batch b's blocks land on XCD b.
#define PACK_CHUNKS ((NCAM * HWPIX) / 256)   // 600 blocks per batch
__global__ void __launch_bounds__(256)
pack_u8(const float* __restrict__ hm, uint4* __restrict__ out)
{
    const int b = blockIdx.x & 7;
    const int chunk = blockIdx.x >> 3;
    const int pix = chunk * 256 + threadIdx.x;      // over N*H*W within batch
    const int n = pix / HWPIX;
    const int yx = pix - n * HWPIX;
    const int bn = b * NCAM + n;
    const float* src = hm + (size_t)bn * NJ * HWPIX + yx;
    unsigned v8[16];
    #pragma unroll
    for (int j = 0; j < NJ; ++j) {
        float v = src[(size_t)j * HWPIX];
        v = fminf(fmaxf(v, 0.0f), 1.0f);
        v8[j] = (unsigned)fmaf(v, 255.0f, 0.5f);
    }
    v8[15] = 0u;
    uint4 q;
    q.x = v8[0]  | (v8[1]  << 8) | (v8[2]  << 16) | (v8[3]  << 24);
    q.y = v8[4]  | (v8[5]  << 8) | (v8[6]  << 16) | (v8[7]  << 24);
    q.z = v8[8]  | (v8[9]  << 8) | (v8[10] << 16) | (v8[11] << 24);
    q.w = v8[12] | (v8[13] << 8) | (v8[14] << 16);
    out[(size_t)bn * HWPIX + yx] = q;
}

struct TapsU {
    int i00, i10, i01, i11;
    float w00, w10, w01, w11, m;
};

__device__ __forceinline__ TapsU make_taps(
    float xc, float yc, float zc,
    float k0, float k1, float k2, float p0, float p1,
    float fx, float fy, float cxx, float cyy,
    float width, float height, float himax,
    float Ax, float Bx, float Ay, float By)
{
    const float inv = 1.0f / (zc + 1e-5f);
    const float yn0 = xc * inv;
    const float yn1 = yc * inv;
    const float r2 = yn0 * yn0 + yn1 * yn1;
    const float radial = 1.0f + k0 * r2 + k1 * (r2 * r2) + k2 * (r2 * r2 * r2);
    const float tan2 = 2.0f * (p0 * yn1 + p1 * yn0);
    const float yd0 = yn0 * (radial + tan2) + p1 * r2;
    const float yd1 = yn1 * (radial + tan2) + p0 * r2;

    float x = fmaf(fx, yd0, cxx);
    float y = fmaf(fy, yd1, cyy);

    const float m = (x >= 0.0f && y >= 0.0f && x < width && y < height) ? 1.0f : 0.0f;

    x = fminf(fmaxf(x, -1.0f), himax);
    y = fminf(fmaxf(y, -1.0f), himax);

    float gx = fmaf(Ax, x, Bx);
    float gy = fmaf(Ay, y, By);
    gx = fminf(fmaxf(gx, -1.1f), 1.1f);
    gy = fminf(fmaxf(gy, -1.1f), 1.1f);
    const float px = (gx + 1.0f) * (0.5f * (HM_W - 1));
    const float py = (gy + 1.0f) * (0.5f * (HM_H - 1));

    const float x0f = floorf(px), y0f = floorf(py);
    const float dx = px - x0f, dy = py - y0f;
    const int x0 = (int)x0f, y0 = (int)y0f;
    const int x1 = x0 + 1, y1 = y0 + 1;

    float w00 = (1.0f - dx) * (1.0f - dy);
    float w10 = dx * (1.0f - dy);
    float w01 = (1.0f - dx) * dy;
    float w11 = dx * dy;

    const bool vx0 = (x0 >= 0) & (x0 < HM_W);
    const bool vx1 = (x1 >= 0) & (x1 < HM_W);
    const bool vy0 = (y0 >= 0) & (y0 < HM_H);
    const bool vy1 = (y1 >= 0) & (y1 < HM_H);

    TapsU t;
    t.w00 = (vx0 && vy0) ? w00 * m : 0.0f;
    t.w10 = (vx1 && vy0) ? w10 * m : 0.0f;
    t.w01 = (vx0 && vy1) ? w01 * m : 0.0f;
    t.w11 = (vx1 && vy1) ? w11 * m : 0.0f;
    t.m = m;

    const int xa = iclamp(x0, 0, HM_W - 1);
    const int xb = iclamp(x1, 0, HM_W - 1);
    const int ya = iclamp(y0, 0, HM_H - 1);
    const int yb = iclamp(y1, 0, HM_H - 1);

    t.i00 = ya * HM_W + xa;
    t.i10 = ya * HM_W + xb;
    t.i01 = yb * HM_W + xa;
    t.i11 = yb * HM_W + xb;
    return t;
}

__device__ __forceinline__ void accum_u8(const uint4* __restrict__ base,
                                         const TapsU& t, float* __restrict__ num)
{
    const uint4 q00 = base[t.i00];
    const uint4 q10 = base[t.i10];
    const uint4 q01 = base[t.i01];
    const uint4 q11 = base[t.i11];
    const unsigned* a00 = (const unsigned*)&q00;
    const unsigned* a10 = (const unsigned*)&q10;
    const unsigned* a01 = (const unsigned*)&q01;
    const unsigned* a11 = (const unsigned*)&q11;
    #pragma unroll
    for (int j = 0; j < NJ; ++j) {
        const int d = j >> 2, sh = (j & 3) * 8;
        const float v00 = (float)((a00[d] >> sh) & 0xffu);   // -> v_cvt_f32_ubyteN
        const float v10 = (float)((a10[d] >> sh) & 0xffu);
        const float v01 = (float)((a01[d] >> sh) & 0xffu);
        const float v11 = (float)((a11[d] >> sh) & 0xffu);
        num[j] = fmaf(t.w00, v00, num[j]);
        num[j] = fmaf(t.w10, v10, num[j]);
        num[j] = fmaf(t.w01, v01, num[j]);
        num[j] = fmaf(t.w11, v11, num[j]);
    }
}

// ---- main kernel: 2 z-adjacent voxels per thread, u8 packed gathers ----
// 1-D grid: blockIdx.x = chunk*8 + b  =>  batch b pinned to XCD b (round-robin
// dispatch), so the batch's 2.4 MB packed working set stays in one L2.
#define PROJ_CHUNKS ((NBINS / 2) / 256)     // 250 blocks per batch
__global__ void __launch_bounds__(256)
project_u8(const uint4* __restrict__ hmp,             // [B,N,H,W] of 16-byte pixels
           const float* __restrict__ grid_center,
           const float* __restrict__ R, const float* __restrict__ T,
           const float* __restrict__ f, const float* __restrict__ c,
           const float* __restrict__ k, const float* __restrict__ p,
           const float* __restrict__ cc, const float* __restrict__ sc,
           float* __restrict__ cubes, float* __restrict__ grids)
{
    const int b = blockIdx.x & 7;
    const int chunk = blockIdx.x >> 3;
    const int v2 = chunk * 256 + threadIdx.x;    // voxel-pair index within batch

    const int col = v2 / (CZ / 2);         // x*CY + y
    const int tz  = v2 - col * (CZ / 2);
    const int ix = col / CY;
    const int iy = col - ix * CY;
    const int iz0 = 2 * tz;
    const int v0 = col * CZ + iz0;

    const float gcx = grid_center[b * 3 + 0];
    const float gcy = grid_center[b * 3 + 1];
    const float gcz = grid_center[b * 3 + 2];

    const float gx = -4000.0f + (float)ix * (8000.0f / 79.0f) + gcx;
    const float gy = -4000.0f + (float)iy * (8000.0f / 79.0f) + gcy;
    const float gz0 = -1000.0f + (float)iz0 * (2000.0f / 19.0f) + gcz;
    const float gz1 = gz0 + (2000.0f / 19.0f);

    {   // grids output: 6 consecutive floats, 8B-aligned -> 3x float2
        float* g = grids + ((size_t)b * NBINS + v0) * 3;
        float2* g2 = reinterpret_cast<float2*>(g);
        g2[0] = make_float2(gx, gy);
        g2[1] = make_float2(gz0, gx);
        g2[2] = make_float2(gy, gz1);
    }

    float num0[NJ], num1[NJ];
    #pragma unroll
    for (int j = 0; j < NJ; ++j) { num0[j] = 0.0f; num1[j] = 0.0f; }
    float den0 = 1e-6f, den1 = 1e-6f;

    for (int n = 0; n < NCAM; ++n) {
        const int bn = b * NCAM + n;
        const float* Rn = R + (size_t)bn * 9;
        const float* Tn = T + (size_t)bn * 3;

        const float X = gx - Tn[0];
        const float Y = gy - Tn[1];
        const float Z0 = gz0 - Tn[2];
        const float Z1 = gz1 - Tn[2];

        const float xp = Rn[0] * X + Rn[1] * Y;
        const float yp = Rn[3] * X + Rn[4] * Y;
        const float zp = Rn[6] * X + Rn[7] * Y;

        const float k0 = k[bn * 3 + 0], k1 = k[bn * 3 + 1], k2 = k[bn * 3 + 2];
        const float p0 = p[bn * 2 + 0], p1 = p[bn * 2 + 1];
        const float fx = f[bn * 2 + 0], fy = f[bn * 2 + 1];
        const float cxx = c[bn * 2 + 0], cyy = c[bn * 2 + 1];
        const float ccx = cc[bn * 2 + 0], ccy = cc[bn * 2 + 1];
        const float width = 2.0f * ccx, height = 2.0f * ccy;
        const float himax = fmaxf(width, height);

        const float inv_h = 1.0f / (200.0f * sc[bn * 2 + 0]);
        const float Ax = (2.0f * (float)HM_W / (float)(HM_W - 1)) * inv_h;
        const float Bx = (0.5f - ccx * inv_h) * (2.0f * (float)HM_W / (float)(HM_W - 1)) - 1.0f;
        const float Ay = (2.0f * (float)HM_H / (float)(HM_H - 1)) * inv_h;
        const float By = (0.5f - ccy * inv_h) * (2.0f * (float)HM_H / (float)(HM_H - 1)) - 1.0f;

        const TapsU t0 = make_taps(fmaf(Rn[2], Z0, xp), fmaf(Rn[5], Z0, yp), fmaf(Rn[8], Z0, zp),
                                   k0, k1, k2, p0, p1, fx, fy, cxx, cyy,
                                   width, height, himax, Ax, Bx, Ay, By);
        const TapsU t1 = make_taps(fmaf(Rn[2], Z1, xp), fmaf(Rn[5], Z1, yp), fmaf(Rn[8], Z1, zp),
                                   k0, k1, k2, p0, p1, fx, fy, cxx, cyy,
                                   width, height, himax, Ax, Bx, Ay, By);

        const uint4* base = hmp + (size_t)bn * HWPIX;
        accum_u8(base, t0, num0);
        accum_u8(base, t1, num1);
        den0 += t0.m;
        den1 += t1.m;
    }

    const float s0 = (1.0f / 255.0f) / den0;
    const float s1 = (1.0f / 255.0f) / den1;
    const size_t outbase = (size_t)b * NJ * NBINS + v0;
    #pragma unroll
    for (int j = 0; j < NJ; ++j) {
        float2 o;
        o.x = fminf(fmaxf(num0[j] * s0, 0.0f), 1.0f);
        o.y = fminf(fmaxf(num1[j] * s1, 0.0f), 1.0f);
        *reinterpret_cast<float2*>(cubes + outbase + (size_t)j * NBINS) = o;
    }
}

// ---- fallback: direct f32 gathers (used only if ws too small) ----
__global__ void __launch_bounds__(256)
project_direct(const float* __restrict__ hm,
               const float* __restrict__ grid_center,
               const float* __restrict__ R, const float* __restrict__ T,
               const float* __restrict__ f, const float* __restrict__ c,
               const float* __restrict__ k, const float* __restrict__ p,
               const float* __restrict__ cc, const float* __restrict__ sc,
               float* __restrict__ cubes, float* __restrict__ grids)
{
    const int b = blockIdx.y;
    const int v = blockIdx.x * blockDim.x + threadIdx.x;
    if (v >= NBINS) return;

    const int ix = v / (CY * CZ);
    const int rem = v - ix * (CY * CZ);
    const int iy = rem / CZ;
    const int iz = rem - iy * CZ;

    const float gx = -4000.0f + (float)ix * (8000.0f / 79.0f) + grid_center[b * 3 + 0];
    const float gy = -4000.0f + (float)iy * (8000.0f / 79.0f) + grid_center[b * 3 + 1];
    const float gz = -1000.0f + (float)iz * (2000.0f / 19.0f) + grid_center[b * 3 + 2];

    {
        float* g = grids + ((size_t)b * NBINS + v) * 3;
        g[0] = gx; g[1] = gy; g[2] = gz;
    }

    float num[NJ];
    #pragma unroll
    for (int j = 0; j < NJ; ++j) num[j] = 0.0f;
    float den = 1e-6f;

    for (int n = 0; n < NCAM; ++n) {
        const int bn = b * NCAM + n;
        const float* Rn = R + (size_t)bn * 9;
        const float* Tn = T + (size_t)bn * 3;
        const float X = gx - Tn[0], Y = gy - Tn[1], Z = gz - Tn[2];

        const float ccx = cc[bn * 2 + 0], ccy = cc[bn * 2 + 1];
        const float width = 2.0f * ccx, height = 2.0f * ccy;
        const float inv_h = 1.0f / (200.0f * sc[bn * 2 + 0]);
        const float Ax = (2.0f * (float)HM_W / (float)(HM_W - 1)) * inv_h;
        const float Bx = (0.5f - ccx * inv_h) * (2.0f * (float)HM_W / (float)(HM_W - 1)) - 1.0f;
        const float Ay = (2.0f * (float)HM_H / (float)(HM_H - 1)) * inv_h;
        const float By = (0.5f - ccy * inv_h) * (2.0f * (float)HM_H / (float)(HM_H - 1)) - 1.0f;

        const TapsU t = make_taps(
            Rn[0]*X + Rn[1]*Y + Rn[2]*Z, Rn[3]*X + Rn[4]*Y + Rn[5]*Z, Rn[6]*X + Rn[7]*Y + Rn[8]*Z,
            k[bn*3+0], k[bn*3+1], k[bn*3+2], p[bn*2+0], p[bn*2+1],
            f[bn*2+0], f[bn*2+1], c[bn*2+0], c[bn*2+1],
            width, height, fmaxf(width, height), Ax, Bx, Ay, By);

        const float* base = hm + (size_t)bn * NJ * HWPIX;
        #pragma unroll
        for (int j = 0; j < NJ; ++j) {
            const float* img = base + (size_t)j * HWPIX;
            num[j] += t.w00 * img[t.i00] + t.w10 * img[t.i10]
                    + t.w01 * img[t.i01] + t.w11 * img[t.i11];
        }
        den += t.m;
    }

    const float invden = 1.0f / den;
    const size_t outbase = (size_t)b * NJ * NBINS + v;
    #pragma unroll
    for (int j = 0; j < NJ; ++j) {
        float val = num[j] * invden;
        val = fminf(fmaxf(val, 0.0f), 1.0f);
        cubes[outbase + (size_t)j * NBINS] = val;
    }
}

extern "C" void kernel_launch(void* const* d_in, const int* in_sizes, int n_in,
                              void* d_out, int out_size, void* d_ws, size_t ws_size,
                              hipStream_t stream) {
    const float* hm = (const float*)d_in[0];
    const float* gc = (const float*)d_in[1];
    const float* R  = (const float*)d_in[2];
    const float* T  = (const float*)d_in[3];
    const float* f  = (const float*)d_in[4];
    const float* c  = (const float*)d_in[5];
    const float* k  = (const float*)d_in[6];
    const float* p  = (const float*)d_in[7];
    const float* cc = (const float*)d_in[8];
    const float* sc = (const float*)d_in[9];

    float* out   = (float*)d_out;
    float* cubes = out;                                  // [B,J,NBINS]
    float* grids = out + (size_t)NB * NJ * NBINS;        // [B,NBINS,3]

    const size_t need = (size_t)NB * NCAM * HWPIX * 16 + 64;
    if (ws_size >= need) {
        uint4* hmp = (uint4*)d_ws;
        hipLaunchKernelGGL(pack_u8, dim3(NB * PACK_CHUNKS), dim3(256), 0, stream,
                           hm, hmp);
        hipLaunchKernelGGL(project_u8, dim3(NB * PROJ_CHUNKS), dim3(256), 0, stream,
                           hmp, gc, R, T, f, c, k, p, cc, sc, cubes, grids);
    } else {
        dim3 grid((NBINS + 255) / 256, NB);
        hipLaunchKernelGGL(project_direct, grid, dim3(256), 0, stream,
                           hm, gc, R, T, f, c, k, p, cc, sc, cubes, grids);
    }
}

// Round 5
// 58.167 us; speedup vs baseline: 7.2168x; 1.0380x over previous
//
#include <hip/hip_runtime.h>

#define HM_W 240
#define HM_H 128
#define NCAM 5
#define NJ   15
#define CX   80
#define CY   80
#define CZ   20
#define NBINS (CX*CY*CZ)
#define NB   8
#define HWPIX (HM_H*HM_W)

__device__ __forceinline__ int iclamp(int x, int lo, int hi) {
    return x < lo ? lo : (x > hi ? hi : x);
}

// ---- pack: [B,N,J,H,W] f32 -> [B,N,H,W,16] u8 (val*255, rounded) ----
// 1-D grid, batch = blockIdx.x & 7 so batch b's blocks land on XCD b.
#define PACK_CHUNKS ((NCAM * HWPIX) / 256)   // 600 blocks per batch
__global__ void __launch_bounds__(256)
pack_u8(const float* __restrict__ hm, uint4* __restrict__ out)
{
    const int b = blockIdx.x & 7;
    const int chunk = blockIdx.x >> 3;
    const int pix = chunk * 256 + threadIdx.x;      // over N*H*W within batch
    const int n = pix / HWPIX;
    const int yx = pix - n * HWPIX;
    const int bn = b * NCAM + n;
    const float* src = hm + (size_t)bn * NJ * HWPIX + yx;
    unsigned v8[16];
    #pragma unroll
    for (int j = 0; j < NJ; ++j) {
        float v = src[(size_t)j * HWPIX];
        v = fminf(fmaxf(v, 0.0f), 1.0f);
        v8[j] = (unsigned)fmaf(v, 255.0f, 0.5f);
    }
    v8[15] = 0u;
    uint4 q;
    q.x = v8[0]  | (v8[1]  << 8) | (v8[2]  << 16) | (v8[3]  << 24);
    q.y = v8[4]  | (v8[5]  << 8) | (v8[6]  << 16) | (v8[7]  << 24);
    q.z = v8[8]  | (v8[9]  << 8) | (v8[10] << 16) | (v8[11] << 24);
    q.w = v8[12] | (v8[13] << 8) | (v8[14] << 16);
    out[(size_t)bn * HWPIX + yx] = q;
}

struct TapsU {
    int i00, i10, i01, i11;
    float w00, w10, w01, w11, m;
};

__device__ __forceinline__ TapsU make_taps(
    float xc, float yc, float zc,
    float k0, float k1, float k2, float p0, float p1,
    float fx, float fy, float cxx, float cyy,
    float width, float height, float himax,
    float Ax, float Bx, float Ay, float By)
{
    const float inv = 1.0f / (zc + 1e-5f);
    const float yn0 = xc * inv;
    const float yn1 = yc * inv;
    const float r2 = yn0 * yn0 + yn1 * yn1;
    const float radial = 1.0f + k0 * r2 + k1 * (r2 * r2) + k2 * (r2 * r2 * r2);
    const float tan2 = 2.0f * (p0 * yn1 + p1 * yn0);
    const float yd0 = yn0 * (radial + tan2) + p1 * r2;
    const float yd1 = yn1 * (radial + tan2) + p0 * r2;

    float x = fmaf(fx, yd0, cxx);
    float y = fmaf(fy, yd1, cyy);

    const float m = (x >= 0.0f && y >= 0.0f && x < width && y < height) ? 1.0f : 0.0f;

    x = fminf(fmaxf(x, -1.0f), himax);
    y = fminf(fmaxf(y, -1.0f), himax);

    float gx = fmaf(Ax, x, Bx);
    float gy = fmaf(Ay, y, By);
    gx = fminf(fmaxf(gx, -1.1f), 1.1f);
    gy = fminf(fmaxf(gy, -1.1f), 1.1f);
    const float px = (gx + 1.0f) * (0.5f * (HM_W - 1));
    const float py = (gy + 1.0f) * (0.5f * (HM_H - 1));

    const float x0f = floorf(px), y0f = floorf(py);
    const float dx = px - x0f, dy = py - y0f;
    const int x0 = (int)x0f, y0 = (int)y0f;
    const int x1 = x0 + 1, y1 = y0 + 1;

    float w00 = (1.0f - dx) * (1.0f - dy);
    float w10 = dx * (1.0f - dy);
    float w01 = (1.0f - dx) * dy;
    float w11 = dx * dy;

    const bool vx0 = (x0 >= 0) & (x0 < HM_W);
    const bool vx1 = (x1 >= 0) & (x1 < HM_W);
    const bool vy0 = (y0 >= 0) & (y0 < HM_H);
    const bool vy1 = (y1 >= 0) & (y1 < HM_H);

    TapsU t;
    t.w00 = (vx0 && vy0) ? w00 * m : 0.0f;
    t.w10 = (vx1 && vy0) ? w10 * m : 0.0f;
    t.w01 = (vx0 && vy1) ? w01 * m : 0.0f;
    t.w11 = (vx1 && vy1) ? w11 * m : 0.0f;
    t.m = m;

    const int xa = iclamp(x0, 0, HM_W - 1);
    const int xb = iclamp(x1, 0, HM_W - 1);
    const int ya = iclamp(y0, 0, HM_H - 1);
    const int yb = iclamp(y1, 0, HM_H - 1);

    t.i00 = ya * HM_W + xa;
    t.i10 = ya * HM_W + xb;
    t.i01 = yb * HM_W + xa;
    t.i11 = yb * HM_W + xb;
    return t;
}

// perm selector notes (v_perm_b32): sel byte 0-3 -> src1 bytes, 4-7 -> src0 bytes.
// pA = [a00.b0, a10.b0, a00.b1, a10.b1]  sel 0x01050004 (src0=a00, src1=a10)
// Vj0 = [pA.b0, pA.b1, pB.b0, pB.b1]     sel 0x01000504 (src0=pA,  src1=pB)
__device__ __forceinline__ void accum_dot(const uint4* __restrict__ base,
                                          const TapsU& t, unsigned* __restrict__ acc)
{
    // packed bilinear weights: byte layout must match V = [v00,v10,v01,v11]
    const unsigned wq0 = (unsigned)fmaf(t.w00, 255.0f, 0.5f);
    const unsigned wq1 = (unsigned)fmaf(t.w10, 255.0f, 0.5f);
    const unsigned wq2 = (unsigned)fmaf(t.w01, 255.0f, 0.5f);
    const unsigned wq3 = (unsigned)fmaf(t.w11, 255.0f, 0.5f);
    const unsigned W = wq0 | (wq1 << 8) | (wq2 << 16) | (wq3 << 24);

    const uint4 q00 = base[t.i00];
    const uint4 q10 = base[t.i10];
    const uint4 q01 = base[t.i01];
    const uint4 q11 = base[t.i11];
    const unsigned* a00 = (const unsigned*)&q00;
    const unsigned* a10 = (const unsigned*)&q10;
    const unsigned* a01 = (const unsigned*)&q01;
    const unsigned* a11 = (const unsigned*)&q11;

    #pragma unroll
    for (int d = 0; d < 4; ++d) {
        const int jb = 4 * d;
        const unsigned pA = __builtin_amdgcn_perm(a00[d], a10[d], 0x01050004u);
        const unsigned pB = __builtin_amdgcn_perm(a01[d], a11[d], 0x01050004u);
        acc[jb + 0] = __builtin_amdgcn_udot4(
            __builtin_amdgcn_perm(pA, pB, 0x01000504u), W, acc[jb + 0], false);
        acc[jb + 1] = __builtin_amdgcn_udot4(
            __builtin_amdgcn_perm(pA, pB, 0x03020706u), W, acc[jb + 1], false);
        const unsigned pC = __builtin_amdgcn_perm(a00[d], a10[d], 0x03070206u);
        const unsigned pD = __builtin_amdgcn_perm(a01[d], a11[d], 0x03070206u);
        acc[jb + 2] = __builtin_amdgcn_udot4(
            __builtin_amdgcn_perm(pC, pD, 0x01000504u), W, acc[jb + 2], false);
        if (jb + 3 < NJ)
            acc[jb + 3] = __builtin_amdgcn_udot4(
                __builtin_amdgcn_perm(pC, pD, 0x03020706u), W, acc[jb + 3], false);
    }
}

// ---- main kernel: 2 z-adjacent voxels per thread, u8 dot4 gathers ----
// 1-D grid: blockIdx.x = chunk*8 + b  =>  batch b pinned to XCD b.
#define PROJ_CHUNKS ((NBINS / 2) / 256)     // 250 blocks per batch
__global__ void __launch_bounds__(256)
project_u8(const uint4* __restrict__ hmp,             // [B,N,H,W] of 16-byte pixels
           const float* __restrict__ grid_center,
           const float* __restrict__ R, const float* __restrict__ T,
           const float* __restrict__ f, const float* __restrict__ c,
           const float* __restrict__ k, const float* __restrict__ p,
           const float* __restrict__ cc, const float* __restrict__ sc,
           float* __restrict__ cubes, float* __restrict__ grids)
{
    const int b = blockIdx.x & 7;
    const int chunk = blockIdx.x >> 3;
    const int v2 = chunk * 256 + threadIdx.x;    // voxel-pair index within batch

    const int col = v2 / (CZ / 2);         // x*CY + y
    const int tz  = v2 - col * (CZ / 2);
    const int ix = col / CY;
    const int iy = col - ix * CY;
    const int iz0 = 2 * tz;
    const int v0 = col * CZ + iz0;

    const float gcx = grid_center[b * 3 + 0];
    const float gcy = grid_center[b * 3 + 1];
    const float gcz = grid_center[b * 3 + 2];

    const float gx = -4000.0f + (float)ix * (8000.0f / 79.0f) + gcx;
    const float gy = -4000.0f + (float)iy * (8000.0f / 79.0f) + gcy;
    const float gz0 = -1000.0f + (float)iz0 * (2000.0f / 19.0f) + gcz;
    const float gz1 = gz0 + (2000.0f / 19.0f);

    {   // grids output: 6 consecutive floats, 8B-aligned -> 3x float2
        float* g = grids + ((size_t)b * NBINS + v0) * 3;
        float2* g2 = reinterpret_cast<float2*>(g);
        g2[0] = make_float2(gx, gy);
        g2[1] = make_float2(gz0, gx);
        g2[2] = make_float2(gy, gz1);
    }

    unsigned acc0[NJ], acc1[NJ];
    #pragma unroll
    for (int j = 0; j < NJ; ++j) { acc0[j] = 0u; acc1[j] = 0u; }
    float den0 = 1e-6f, den1 = 1e-6f;

    for (int n = 0; n < NCAM; ++n) {
        const int bn = b * NCAM + n;
        const float* Rn = R + (size_t)bn * 9;
        const float* Tn = T + (size_t)bn * 3;

        const float X = gx - Tn[0];
        const float Y = gy - Tn[1];
        const float Z0 = gz0 - Tn[2];
        const float Z1 = gz1 - Tn[2];

        const float xp = Rn[0] * X + Rn[1] * Y;
        const float yp = Rn[3] * X + Rn[4] * Y;
        const float zp = Rn[6] * X + Rn[7] * Y;

        const float k0 = k[bn * 3 + 0], k1 = k[bn * 3 + 1], k2 = k[bn * 3 + 2];
        const float p0 = p[bn * 2 + 0], p1 = p[bn * 2 + 1];
        const float fx = f[bn * 2 + 0], fy = f[bn * 2 + 1];
        const float cxx = c[bn * 2 + 0], cyy = c[bn * 2 + 1];
        const float ccx = cc[bn * 2 + 0], ccy = cc[bn * 2 + 1];
        const float width = 2.0f * ccx, height = 2.0f * ccy;
        const float himax = fmaxf(width, height);

        const float inv_h = 1.0f / (200.0f * sc[bn * 2 + 0]);
        const float Ax = (2.0f * (float)HM_W / (float)(HM_W - 1)) * inv_h;
        const float Bx = (0.5f - ccx * inv_h) * (2.0f * (float)HM_W / (float)(HM_W - 1)) - 1.0f;
        const float Ay = (2.0f * (float)HM_H / (float)(HM_H - 1)) * inv_h;
        const float By = (0.5f - ccy * inv_h) * (2.0f * (float)HM_H / (float)(HM_H - 1)) - 1.0f;

        const TapsU t0 = make_taps(fmaf(Rn[2], Z0, xp), fmaf(Rn[5], Z0, yp), fmaf(Rn[8], Z0, zp),
                                   k0, k1, k2, p0, p1, fx, fy, cxx, cyy,
                                   width, height, himax, Ax, Bx, Ay, By);
        const TapsU t1 = make_taps(fmaf(Rn[2], Z1, xp), fmaf(Rn[5], Z1, yp), fmaf(Rn[8], Z1, zp),
                                   k0, k1, k2, p0, p1, fx, fy, cxx, cyy,
                                   width, height, himax, Ax, Bx, Ay, By);

        const uint4* base = hmp + (size_t)bn * HWPIX;
        accum_dot(base, t0, acc0);
        accum_dot(base, t1, acc1);
        den0 += t0.m;
        den1 += t1.m;
    }

    const float s0 = (1.0f / 65025.0f) / den0;   // 65025 = 255*255
    const float s1 = (1.0f / 65025.0f) / den1;
    const size_t outbase = (size_t)b * NJ * NBINS + v0;
    #pragma unroll
    for (int j = 0; j < NJ; ++j) {
        float2 o;
        o.x = fminf((float)acc0[j] * s0, 1.0f);   // acc >= 0, lower clamp free
        o.y = fminf((float)acc1[j] * s1, 1.0f);
        *reinterpret_cast<float2*>(cubes + outbase + (size_t)j * NBINS) = o;
    }
}

// ---- fallback: direct f32 gathers (used only if ws too small) ----
__global__ void __launch_bounds__(256)
project_direct(const float* __restrict__ hm,
               const float* __restrict__ grid_center,
               const float* __restrict__ R, const float* __restrict__ T,
               const float* __restrict__ f, const float* __restrict__ c,
               const float* __restrict__ k, const float* __restrict__ p,
               const float* __restrict__ cc, const float* __restrict__ sc,
               float* __restrict__ cubes, float* __restrict__ grids)
{
    const int b = blockIdx.y;
    const int v = blockIdx.x * blockDim.x + threadIdx.x;
    if (v >= NBINS) return;

    const int ix = v / (CY * CZ);
    const int rem = v - ix * (CY * CZ);
    const int iy = rem / CZ;
    const int iz = rem - iy * CZ;

    const float gx = -4000.0f + (float)ix * (8000.0f / 79.0f) + grid_center[b * 3 + 0];
    const float gy = -4000.0f + (float)iy * (8000.0f / 79.0f) + grid_center[b * 3 + 1];
    const float gz = -1000.0f + (float)iz * (2000.0f / 19.0f) + grid_center[b * 3 + 2];

    {
        float* g = grids + ((size_t)b * NBINS + v) * 3;
        g[0] = gx; g[1] = gy; g[2] = gz;
    }

    float num[NJ];
    #pragma unroll
    for (int j = 0; j < NJ; ++j) num[j] = 0.0f;
    float den = 1e-6f;

    for (int n = 0; n < NCAM; ++n) {
        const int bn = b * NCAM + n;
        const float* Rn = R + (size_t)bn * 9;
        const float* Tn = T + (size_t)bn * 3;
        const float X = gx - Tn[0], Y = gy - Tn[1], Z = gz - Tn[2];

        const float ccx = cc[bn * 2 + 0], ccy = cc[bn * 2 + 1];
        const float width = 2.0f * ccx, height = 2.0f * ccy;
        const float inv_h = 1.0f / (200.0f * sc[bn * 2 + 0]);
        const float Ax = (2.0f * (float)HM_W / (float)(HM_W - 1)) * inv_h;
        const float Bx = (0.5f - ccx * inv_h) * (2.0f * (float)HM_W / (float)(HM_W - 1)) - 1.0f;
        const float Ay = (2.0f * (float)HM_H / (float)(HM_H - 1)) * inv_h;
        const float By = (0.5f - ccy * inv_h) * (2.0f * (float)HM_H / (float)(HM_H - 1)) - 1.0f;

        const TapsU t = make_taps(
            Rn[0]*X + Rn[1]*Y + Rn[2]*Z, Rn[3]*X + Rn[4]*Y + Rn[5]*Z, Rn[6]*X + Rn[7]*Y + Rn[8]*Z,
            k[bn*3+0], k[bn*3+1], k[bn*3+2], p[bn*2+0], p[bn*2+1],
            f[bn*2+0], f[bn*2+1], c[bn*2+0], c[bn*2+1],
            width, height, fmaxf(width, height), Ax, Bx, Ay, By);

        const float* base = hm + (size_t)bn * NJ * HWPIX;
        #pragma unroll
        for (int j = 0; j < NJ; ++j) {
            const float* img = base + (size_t)j * HWPIX;
            num[j] += t.w00 * img[t.i00] + t.w10 * img[t.i10]
                    + t.w01 * img[t.i01] + t.w11 * img[t.i11];
        }
        den += t.m;
    }

    const float invden = 1.0f / den;
    const size_t outbase = (size_t)b * NJ * NBINS + v;
    #pragma unroll
    for (int j = 0; j < NJ; ++j) {
        float val = num[j] * invden;
        val = fminf(fmaxf(val, 0.0f), 1.0f);
        cubes[outbase + (size_t)j * NBINS] = val;
    }
}

extern "C" void kernel_launch(void* const* d_in, const int* in_sizes, int n_in,
                              void* d_out, int out_size, void* d_ws, size_t ws_size,
                              hipStream_t stream) {
    const float* hm = (const float*)d_in[0];
    const float* gc = (const float*)d_in[1];
    const float* R  = (const float*)d_in[2];
    const float* T  = (const float*)d_in[3];
    const float* f  = (const float*)d_in[4];
    const float* c  = (const float*)d_in[5];
    const float* k  = (const float*)d_in[6];
    const float* p  = (const float*)d_in[7];
    const float* cc = (const float*)d_in[8];
    const float* sc = (const float*)d_in[9];

    float* out   = (float*)d_out;
    float* cubes = out;                                  // [B,J,NBINS]
    float* grids = out + (size_t)NB * NJ * NBINS;        // [B,NBINS,3]

    const size_t need = (size_t)NB * NCAM * HWPIX * 16 + 64;
    if (ws_size >= need) {
        uint4* hmp = (uint4*)d_ws;
        hipLaunchKernelGGL(pack_u8, dim3(NB * PACK_CHUNKS), dim3(256), 0, stream,
                           hm, hmp);
        hipLaunchKernelGGL(project_u8, dim3(NB * PROJ_CHUNKS), dim3(256), 0, stream,
                           hmp, gc, R, T, f, c, k, p, cc, sc, cubes, grids);
    } else {
        dim3 grid((NBINS + 255) / 256, NB);
        hipLaunchKernelGGL(project_direct, grid, dim3(256), 0, stream,
                           hm, gc, R, T, f, c, k, p, cc, sc, cubes, grids);
    }
}